// Round 27
// baseline (45.797 us; speedup 1.0000x reference)
//
#include <hip/hip_runtime.h>
#include <hip/hip_fp16.h>

typedef _Float16 half8 __attribute__((ext_vector_type(8)));
typedef _Float16 half4v __attribute__((ext_vector_type(4)));
typedef float float4v __attribute__((ext_vector_type(4)));

#define E_DIM 300
#define KP 320               // padded K (10 MFMA k-steps of 32)
#define B_ 32
#define NROW_CDD 3200        // 32*5*20
#define NROW_HIS 32000       // 32*50*20

typedef const void __attribute__((address_space(1))) gvoid;
typedef void __attribute__((address_space(3))) lvoid;
__device__ __forceinline__ void gload16(const void* g, void* l) {
    __builtin_amdgcn_global_load_lds((gvoid*)g, (lvoid*)l, 16, 0, 0);
}

// ---------------- Kernel 1: gather + l2-normalize (float4 loads, half4 stores) ----------
// grid 8800, 256 threads = 4 rows/block. [R23/R25/R26 verified]
__global__ __launch_bounds__(256) void gather_norm(const int* __restrict__ cand,
                                                   const int* __restrict__ clk,
                                                   const float* __restrict__ emb,
                                                   _Float16* __restrict__ outH)
{
    int row  = blockIdx.x * 4 + (threadIdx.x >> 6);
    int lane = threadIdx.x & 63;
    int tok = (row < NROW_CDD) ? cand[row] : clk[row - NROW_CDD];
    const float4* e4 = (const float4*)(emb + (size_t)tok * E_DIM);   // 75 float4/row

    float4 v0 = e4[lane];
    float4 v1 = {0.f, 0.f, 0.f, 0.f};
    if (lane < 11) v1 = e4[64 + lane];
    float ss = v0.x*v0.x + v0.y*v0.y + v0.z*v0.z + v0.w*v0.w
             + v1.x*v1.x + v1.y*v1.y + v1.z*v1.z + v1.w*v1.w;
#pragma unroll
    for (int off = 32; off; off >>= 1) ss += __shfl_xor(ss, off);
    float sc = 1.0f / fmaxf(sqrtf(ss), 1e-12f);

    _Float16* o = outH + (size_t)row * KP;
    half4v h0 = { (_Float16)(v0.x*sc), (_Float16)(v0.y*sc), (_Float16)(v0.z*sc), (_Float16)(v0.w*sc) };
    *(half4v*)(o + 4 * lane) = h0;
    if (lane < 11) {
        half4v h1 = { (_Float16)(v1.x*sc), (_Float16)(v1.y*sc), (_Float16)(v1.z*sc), (_Float16)(v1.w*sc) };
        *(half4v*)(o + 256 + 4 * lane) = h1;
    } else if (lane < 16) {
        half4v hz = { (_Float16)0.f, (_Float16)0.f, (_Float16)0.f, (_Float16)0.f };
        *(half4v*)(o + 256 + 4 * lane) = hz;      // zero k = 300..319
    }
}

// ---------------- Kernel 2: hybrid GEMM, 32-col tiles, 4 blocks/CU ----------------------
// grid (32, 32) = 1024 blocks, 448 threads (7 waves). A af[10] in regs; B 32x640B via
// 20 global_load_lds segments. LDS 26.9 KB + VGPR cap 73 (launch_bounds 448,7)
// -> 4 blocks/CU: staggered stage bursts overlap other blocks' k-loops.
__global__ __launch_bounds__(448, 7) void sim_gemm(const _Float16* __restrict__ wsH,
                                                   _Float16* __restrict__ simW)
{
    __shared__ __align__(1024) char Bbuf[32 * 640];       // 20480 B, 20 DMA segments
    __shared__ _Float16 simT[100 * 32];                   // 6400 B, stride 32

    int b = blockIdx.y, ntile = blockIdx.x;               // cols ntile*32..+31
    int tid = threadIdx.x;
    int wave = tid >> 6, lane = tid & 63;
    int g4 = lane >> 4, r16 = lane & 15;

    const char* gA = (const char*)(wsH + (size_t)b * 100 * KP);
    const char* gB = (const char*)(wsH + (size_t)(NROW_CDD + b * 1000 + ntile * 32) * KP);

    // ---- hoist A slice: 10 independent global 16B loads (this wave's 16 rows) ----
    int rA = wave * 16 + r16; if (rA > 99) rA = 99;
    const char* pA = gA + (size_t)rA * 640;
    half8 af[10];
#pragma unroll
    for (int k = 0; k < 10; ++k) af[k] = *(const half8*)(pA + k * 64 + g4 * 16);

    // ---- async stage B: 20 x 1024-B segments via global_load_lds (w=16) ----
    // dest = s*1024 + lane*16; src = dest ^ ((row&7)<<4) (in-row: 640 % 32 == 0).
    // ntile 31 rows 8..31 overread in-allocation; cols >= 1000 discarded at write-out.
#pragma unroll
    for (int c = 0; c < 3; ++c) {
        int s = wave * 3 + c;
        if (s < 20) {
            int dest = s * 1024 + lane * 16;
            int r = dest / 640;
            int src = dest ^ ((r & 7) << 4);
            gload16(gB + src, Bbuf + s * 1024);
        }
    }
    __syncthreads();   // drains vmcnt(0) incl. DMA

    // ---- k-loop: 2 ds_read_b128 + 2 MFMA per k ----
    float4v acc[2];
    acc[0] = (float4v){0.f, 0.f, 0.f, 0.f};
    acc[1] = (float4v){0.f, 0.f, 0.f, 0.f};

#pragma unroll
    for (int k = 0; k < 10; ++k) {
#pragma unroll
        for (int n = 0; n < 2; ++n) {
            int rB = n * 16 + r16;
            half8 bf = *(const half8*)(Bbuf + ((rB * 640 + k * 64 + g4 * 16) ^ ((rB & 7) << 4)));
            acc[n] = __builtin_amdgcn_mfma_f32_16x16x32_f16(af[k], bf, acc[n], 0, 0, 0);
        }
    }

    // C/D layout (validated r1-r26): col = lane&15 (B-row), row = (lane>>4)*4+j (A-row)
#pragma unroll
    for (int n = 0; n < 2; ++n) {
#pragma unroll
        for (int j = 0; j < 4; ++j) {
            int r = wave * 16 + g4 * 4 + j;
            if (r < 100) simT[r * 32 + n * 16 + r16] = (_Float16)acc[n][j];
        }
    }
    __syncthreads();

    // ---- coalesced fp16 write-out: 100 rows x 32 cols (800 half4 units) ----
    for (int u = tid; u < 800; u += 448) {
        int r = u >> 3, c4 = u & 7;
        int gcol = ntile * 32 + c4 * 4;
        if (gcol < 1000)
            *(half4v*)(simW + (size_t)(b * 100 + r) * 1000 + gcol) =
                *(half4v*)(simT + r * 32 + c4 * 4);
    }
}

// ---------------- Kernel 3: gaussian kernels + log pooling, one block per sim row -------
__global__ __launch_bounds__(256) void knrm_pool(const _Float16* __restrict__ simW,
                                                 const float* __restrict__ cpad,
                                                 const float* __restrict__ hpad,
                                                 const float* __restrict__ ltr_w,
                                                 float* __restrict__ rowsum)
{
    __shared__ float sS[50 * 21];
    __shared__ float mS[50 * 21];
    __shared__ float wS[1000];
    __shared__ float part[4];

    int row = blockIdx.x;            // (b*5+c)*20 + s
    int b = row / 100;
    int tid = threadIdx.x;

    if (tid < 250) {
        int p = tid * 4;
        half4v hv = *(const half4v*)(simW + (size_t)row * 1000 + p);
        float4v mv = *(const float4v*)(hpad + (size_t)b * 1000 + p);
        *(float4v*)&wS[p] = *(const float4v*)(ltr_w + p);
#pragma unroll
        for (int q = 0; q < 4; ++q) {
            int pq = p + q, h = pq / 20, t = pq - h * 20;
            sS[h * 21 + t] = (float)hv[q];
            mS[h * 21 + t] = mv[q];
        }
    }
    __syncthreads();

    float val = 0.f;
    if (tid < 250) {
        int h = tid % 50, kq = tid / 50;     // kq 0..4, k = kq*4+j
        float bj[4], cj[4];
        bool is19[4];
#pragma unroll
        for (int j = 0; j < 4; ++j) {
            float mu = -0.9f + 0.1f * (float)(kq * 4 + j);
            bj[j] = 100.0f * mu;
            cj[j] = -50.0f * mu * mu;
            is19[j] = (kq * 4 + j) == 19;
        }
        float psum0 = 0.f, psum1 = 0.f, psum2 = 0.f, psum3 = 0.f;
        const float* sp = sS + h * 21;
        const float* mp = mS + h * 21;
#pragma unroll 4
        for (int t = 0; t < 20; ++t) {
            float s  = sp[t];
            float mm = mp[t];
            float d  = s - 1.0f;
            float arg19 = -500000.0f * d * d;
            float a0 = is19[0] ? arg19 : fmaf(fmaf(-50.0f, s, bj[0]), s, cj[0]);
            float a1 = is19[1] ? arg19 : fmaf(fmaf(-50.0f, s, bj[1]), s, cj[1]);
            float a2 = is19[2] ? arg19 : fmaf(fmaf(-50.0f, s, bj[2]), s, cj[2]);
            float a3 = is19[3] ? arg19 : fmaf(fmaf(-50.0f, s, bj[3]), s, cj[3]);
            psum0 = fmaf(__expf(a0), mm, psum0);
            psum1 = fmaf(__expf(a1), mm, psum1);
            psum2 = fmaf(__expf(a2), mm, psum2);
            psum3 = fmaf(__expf(a3), mm, psum3);
        }
        const float* wp = wS + h * 20 + kq * 4;
        val  = __logf(fmaxf(psum0, 1e-10f)) * wp[0];
        val += __logf(fmaxf(psum1, 1e-10f)) * wp[1];
        val += __logf(fmaxf(psum2, 1e-10f)) * wp[2];
        val += __logf(fmaxf(psum3, 1e-10f)) * wp[3];
    }
#pragma unroll
    for (int off = 32; off; off >>= 1) val += __shfl_down(val, off);
    int wave = tid >> 6, lane = tid & 63;
    if (lane == 0) part[wave] = val;
    __syncthreads();
    if (tid == 0)
        rowsum[row] = (part[0] + part[1] + part[2] + part[3]) * 0.01f * cpad[row];
}

// ---------------- Kernel 4: sum rows per (b,c) + bias + log_softmax over C=5 ------------
__global__ __launch_bounds__(64) void finalize(const float* __restrict__ rowsum,
                                               const float* __restrict__ ltr_b,
                                               float* __restrict__ out)
{
    int b = blockIdx.x;
    int tid = threadIdx.x;
    __shared__ float sc[5];
    if (tid < 5) {
        float a = ltr_b[0];
        const float* rp = rowsum + (b * 5 + tid) * 20;
#pragma unroll
        for (int s = 0; s < 20; ++s) a += rp[s];
        sc[tid] = a;
    }
    __syncthreads();
    if (tid < 5) {
        float m = fmaxf(fmaxf(fmaxf(sc[0], sc[1]), fmaxf(sc[2], sc[3])), sc[4]);
        float sum = 0.f;
#pragma unroll
        for (int i = 0; i < 5; ++i) sum += __expf(sc[i] - m);
        out[b * 5 + tid] = sc[tid] - m - __logf(sum);
    }
}

extern "C" void kernel_launch(void* const* d_in, const int* in_sizes, int n_in,
                              void* d_out, int out_size, void* d_ws, size_t ws_size,
                              hipStream_t stream)
{
    const int*   cand = (const int*)d_in[0];
    const int*   clk  = (const int*)d_in[1];
    const float* cpad = (const float*)d_in[2];
    const float* hpad = (const float*)d_in[3];
    const float* emb  = (const float*)d_in[4];
    const float* lw   = (const float*)d_in[5];
    const float* lb   = (const float*)d_in[6];
    float* out = (float*)d_out;

    _Float16* wsH  = (_Float16*)d_ws;                                                   // 22.528 MB
    _Float16* simW = (_Float16*)((char*)d_ws + (size_t)(NROW_CDD + NROW_HIS) * KP * 2); // 6.4 MB
    float* rowsum  = (float*)((char*)simW + (size_t)B_ * 100 * 1000 * 2);               // 12.8 KB

    hipLaunchKernelGGL(gather_norm, dim3((NROW_CDD + NROW_HIS) / 4), dim3(256), 0, stream,
                       cand, clk, emb, wsH);
    hipLaunchKernelGGL(sim_gemm, dim3(32, B_), dim3(448), 0, stream, wsH, simW);
    hipLaunchKernelGGL(knrm_pool, dim3(NROW_CDD), dim3(256), 0, stream,
                       simW, cpad, hpad, lw, rowsum);
    hipLaunchKernelGGL(finalize, dim3(B_), dim3(64), 0, stream, rowsum, lb, out);
}

// Round 28
// 43.462 us; speedup vs baseline: 1.0537x; 1.0537x over previous
//
#include <hip/hip_runtime.h>
#include <hip/hip_fp16.h>

typedef _Float16 half8 __attribute__((ext_vector_type(8)));
typedef _Float16 half4v __attribute__((ext_vector_type(4)));
typedef float float4v __attribute__((ext_vector_type(4)));

#define E_DIM 300
#define KP 320               // padded K (10 MFMA k-steps of 32)
#define B_ 32
#define NROW_CDD 3200        // 32*5*20
#define NROW_HIS 32000       // 32*50*20

typedef const void __attribute__((address_space(1))) gvoid;
typedef void __attribute__((address_space(3))) lvoid;
__device__ __forceinline__ void gload16(const void* g, void* l) {
    __builtin_amdgcn_global_load_lds((gvoid*)g, (lvoid*)l, 16, 0, 0);
}

// ---------------- Kernel 1: gather + l2-normalize (float4 loads, half4 stores) ----------
// grid 8800, 256 threads = 4 rows/block. Scatter/byte-bound (~13 us, near floor).
__global__ __launch_bounds__(256) void gather_norm(const int* __restrict__ cand,
                                                   const int* __restrict__ clk,
                                                   const float* __restrict__ emb,
                                                   _Float16* __restrict__ outH)
{
    int row  = blockIdx.x * 4 + (threadIdx.x >> 6);
    int lane = threadIdx.x & 63;
    int tok = (row < NROW_CDD) ? cand[row] : clk[row - NROW_CDD];
    const float4* e4 = (const float4*)(emb + (size_t)tok * E_DIM);   // 75 float4/row

    float4 v0 = e4[lane];
    float4 v1 = {0.f, 0.f, 0.f, 0.f};
    if (lane < 11) v1 = e4[64 + lane];
    float ss = v0.x*v0.x + v0.y*v0.y + v0.z*v0.z + v0.w*v0.w
             + v1.x*v1.x + v1.y*v1.y + v1.z*v1.z + v1.w*v1.w;
#pragma unroll
    for (int off = 32; off; off >>= 1) ss += __shfl_xor(ss, off);
    float sc = 1.0f / fmaxf(sqrtf(ss), 1e-12f);

    _Float16* o = outH + (size_t)row * KP;
    half4v h0 = { (_Float16)(v0.x*sc), (_Float16)(v0.y*sc), (_Float16)(v0.z*sc), (_Float16)(v0.w*sc) };
    *(half4v*)(o + 4 * lane) = h0;
    if (lane < 11) {
        half4v h1 = { (_Float16)(v1.x*sc), (_Float16)(v1.y*sc), (_Float16)(v1.z*sc), (_Float16)(v1.w*sc) };
        *(half4v*)(o + 256 + 4 * lane) = h1;
    } else if (lane < 16) {
        half4v hz = { (_Float16)0.f, (_Float16)0.f, (_Float16)0.f, (_Float16)0.f };
        *(half4v*)(o + 256 + 4 * lane) = hz;      // zero k = 300..319
    }
}

// ---------------- Kernel 2: hybrid GEMM, async-DMA B staging [R26 best: 43.7 us] --------
// grid (16, 32) = 512 blocks, 448 threads (7 waves). A af[10] in regs; B via 40x1024B
// global_load_lds segments (linear dest, pre-swizzled source). LDS 53760 B.
__global__ __launch_bounds__(448, 6) void sim_gemm(const _Float16* __restrict__ wsH,
                                                   _Float16* __restrict__ simW)
{
    __shared__ __align__(1024) char Bbuf[64 * 640];       // 40960 B, 40 DMA segments
    __shared__ _Float16 simT[100 * 64];                   // 12800 B, stride 64

    int b = blockIdx.y, ntile = blockIdx.x;               // cols ntile*64..+63
    int tid = threadIdx.x;
    int wave = tid >> 6, lane = tid & 63;
    int g4 = lane >> 4, r16 = lane & 15;

    const char* gA = (const char*)(wsH + (size_t)b * 100 * KP);
    const char* gB = (const char*)(wsH + (size_t)(NROW_CDD + b * 1000 + ntile * 64) * KP);

    // ---- hoist A slice: 10 independent global 16B loads (this wave's 16 rows) ----
    int rA = wave * 16 + r16; if (rA > 99) rA = 99;
    const char* pA = gA + (size_t)rA * 640;
    half8 af[10];
#pragma unroll
    for (int k = 0; k < 10; ++k) af[k] = *(const half8*)(pA + k * 64 + g4 * 16);

    // ---- async stage B: 40 x 1024-B segments via global_load_lds (w=16) ----
    // dest = s*1024 + lane*16 (HW: uniform base + lane*16); src = dest ^ ((row&7)<<4)
    // (in-row: 640 % 32 == 0). ntile 15 rows 40..63 overread in-allocation; cols >=1000
    // discarded at write-out.
#pragma unroll
    for (int c = 0; c < 6; ++c) {
        int s = wave * 6 + c;
        if (s < 40) {
            int dest = s * 1024 + lane * 16;
            int r = dest / 640;
            int src = dest ^ ((r & 7) << 4);
            gload16(gB + src, Bbuf + s * 1024);
        }
    }
    __syncthreads();   // drains vmcnt(0) incl. the DMA loads

    // ---- k-loop: 4 ds_read_b128 + 4 MFMA per k (XOR-swizzled reads) ----
    float4v acc[4];
#pragma unroll
    for (int n = 0; n < 4; ++n) acc[n] = (float4v){0.f, 0.f, 0.f, 0.f};

#pragma unroll
    for (int k = 0; k < 10; ++k) {
#pragma unroll
        for (int n = 0; n < 4; ++n) {
            int rB = n * 16 + r16;
            half8 bf = *(const half8*)(Bbuf + ((rB * 640 + k * 64 + g4 * 16) ^ ((rB & 7) << 4)));
            acc[n] = __builtin_amdgcn_mfma_f32_16x16x32_f16(af[k], bf, acc[n], 0, 0, 0);
        }
    }

    // C/D layout (validated r1-r27): col = lane&15 (B-row), row = (lane>>4)*4+j (A-row)
#pragma unroll
    for (int n = 0; n < 4; ++n) {
#pragma unroll
        for (int j = 0; j < 4; ++j) {
            int r = wave * 16 + g4 * 4 + j;
            if (r < 100) simT[r * 64 + n * 16 + r16] = (_Float16)acc[n][j];
        }
    }
    __syncthreads();

    // ---- coalesced fp16 write-out: 100 rows x 64 cols (half4 units) ----
    for (int u = tid; u < 1600; u += 448) {
        int r = u >> 4, c4 = u & 15;
        int gcol = ntile * 64 + c4 * 4;
        if (gcol < 1000)
            *(half4v*)(simW + (size_t)(b * 100 + r) * 1000 + gcol) =
                *(half4v*)(simT + r * 64 + c4 * 4);
    }
}

// ---------------- Kernel 3: gaussian kernels + log pooling, one block per sim row -------
// At the v_exp transcendental floor (~4.8 us).
__global__ __launch_bounds__(256) void knrm_pool(const _Float16* __restrict__ simW,
                                                 const float* __restrict__ cpad,
                                                 const float* __restrict__ hpad,
                                                 const float* __restrict__ ltr_w,
                                                 float* __restrict__ rowsum)
{
    __shared__ float sS[50 * 21];
    __shared__ float mS[50 * 21];
    __shared__ float wS[1000];
    __shared__ float part[4];

    int row = blockIdx.x;            // (b*5+c)*20 + s
    int b = row / 100;
    int tid = threadIdx.x;

    if (tid < 250) {
        int p = tid * 4;
        half4v hv = *(const half4v*)(simW + (size_t)row * 1000 + p);
        float4v mv = *(const float4v*)(hpad + (size_t)b * 1000 + p);
        *(float4v*)&wS[p] = *(const float4v*)(ltr_w + p);
#pragma unroll
        for (int q = 0; q < 4; ++q) {
            int pq = p + q, h = pq / 20, t = pq - h * 20;
            sS[h * 21 + t] = (float)hv[q];
            mS[h * 21 + t] = mv[q];
        }
    }
    __syncthreads();

    float val = 0.f;
    if (tid < 250) {
        int h = tid % 50, kq = tid / 50;     // kq 0..4, k = kq*4+j
        float bj[4], cj[4];
        bool is19[4];
#pragma unroll
        for (int j = 0; j < 4; ++j) {
            float mu = -0.9f + 0.1f * (float)(kq * 4 + j);
            bj[j] = 100.0f * mu;
            cj[j] = -50.0f * mu * mu;
            is19[j] = (kq * 4 + j) == 19;
        }
        float psum0 = 0.f, psum1 = 0.f, psum2 = 0.f, psum3 = 0.f;
        const float* sp = sS + h * 21;
        const float* mp = mS + h * 21;
#pragma unroll 4
        for (int t = 0; t < 20; ++t) {
            float s  = sp[t];
            float mm = mp[t];
            float d  = s - 1.0f;
            float arg19 = -500000.0f * d * d;
            float a0 = is19[0] ? arg19 : fmaf(fmaf(-50.0f, s, bj[0]), s, cj[0]);
            float a1 = is19[1] ? arg19 : fmaf(fmaf(-50.0f, s, bj[1]), s, cj[1]);
            float a2 = is19[2] ? arg19 : fmaf(fmaf(-50.0f, s, bj[2]), s, cj[2]);
            float a3 = is19[3] ? arg19 : fmaf(fmaf(-50.0f, s, bj[3]), s, cj[3]);
            psum0 = fmaf(__expf(a0), mm, psum0);
            psum1 = fmaf(__expf(a1), mm, psum1);
            psum2 = fmaf(__expf(a2), mm, psum2);
            psum3 = fmaf(__expf(a3), mm, psum3);
        }
        const float* wp = wS + h * 20 + kq * 4;
        val  = __logf(fmaxf(psum0, 1e-10f)) * wp[0];
        val += __logf(fmaxf(psum1, 1e-10f)) * wp[1];
        val += __logf(fmaxf(psum2, 1e-10f)) * wp[2];
        val += __logf(fmaxf(psum3, 1e-10f)) * wp[3];
    }
#pragma unroll
    for (int off = 32; off; off >>= 1) val += __shfl_down(val, off);
    int wave = tid >> 6, lane = tid & 63;
    if (lane == 0) part[wave] = val;
    __syncthreads();
    if (tid == 0)
        rowsum[row] = (part[0] + part[1] + part[2] + part[3]) * 0.01f * cpad[row];
}

// ---------------- Kernel 4: sum rows per (b,c) + bias + log_softmax over C=5 ------------
__global__ __launch_bounds__(64) void finalize(const float* __restrict__ rowsum,
                                               const float* __restrict__ ltr_b,
                                               float* __restrict__ out)
{
    int b = blockIdx.x;
    int tid = threadIdx.x;
    __shared__ float sc[5];
    if (tid < 5) {
        float a = ltr_b[0];
        const float* rp = rowsum + (b * 5 + tid) * 20;
#pragma unroll
        for (int s = 0; s < 20; ++s) a += rp[s];
        sc[tid] = a;
    }
    __syncthreads();
    if (tid < 5) {
        float m = fmaxf(fmaxf(fmaxf(sc[0], sc[1]), fmaxf(sc[2], sc[3])), sc[4]);
        float sum = 0.f;
#pragma unroll
        for (int i = 0; i < 5; ++i) sum += __expf(sc[i] - m);
        out[b * 5 + tid] = sc[tid] - m - __logf(sum);
    }
}

extern "C" void kernel_launch(void* const* d_in, const int* in_sizes, int n_in,
                              void* d_out, int out_size, void* d_ws, size_t ws_size,
                              hipStream_t stream)
{
    const int*   cand = (const int*)d_in[0];
    const int*   clk  = (const int*)d_in[1];
    const float* cpad = (const float*)d_in[2];
    const float* hpad = (const float*)d_in[3];
    const float* emb  = (const float*)d_in[4];
    const float* lw   = (const float*)d_in[5];
    const float* lb   = (const float*)d_in[6];
    float* out = (float*)d_out;

    _Float16* wsH  = (_Float16*)d_ws;                                                   // 22.528 MB
    _Float16* simW = (_Float16*)((char*)d_ws + (size_t)(NROW_CDD + NROW_HIS) * KP * 2); // 6.4 MB
    float* rowsum  = (float*)((char*)simW + (size_t)B_ * 100 * 1000 * 2);               // 12.8 KB

    hipLaunchKernelGGL(gather_norm, dim3((NROW_CDD + NROW_HIS) / 4), dim3(256), 0, stream,
                       cand, clk, emb, wsH);
    hipLaunchKernelGGL(sim_gemm, dim3(16, B_), dim3(448), 0, stream, wsH, simW);
    hipLaunchKernelGGL(knrm_pool, dim3(NROW_CDD), dim3(256), 0, stream,
                       simW, cpad, hpad, lw, rowsum);
    hipLaunchKernelGGL(finalize, dim3(B_), dim3(64), 0, stream, rowsum, lb, out);
}